// Round 10
// baseline (3902.848 us; speedup 1.0000x reference)
//
#include <hip/hip_runtime.h>

#define DEVI static __device__ __forceinline__

typedef float    f32x4 __attribute__((ext_vector_type(4)));
typedef _Float16 f16x8 __attribute__((ext_vector_type(8)));

static constexpr int Bn = 8, Ln = 4096, Dn = 1024, Hn = 16, DKn = 64;
static constexpr int TOPK = 8;
static constexpr float LO_SCALE = 2048.f, LO_INV = 1.f / 2048.f;
static constexpr int QSTRIDE = Bn * Hn * Ln;   // corr-partial quarter stride

DEVI f32x4 mfma_f16(f16x8 a, f16x8 b, f32x4 c) {
    return __builtin_amdgcn_mfma_f32_16x16x32_f16(a, b, c, 0, 0, 0);
}

struct HL { _Float16 hi, lo; };
// split f32 -> f16 hi + f16 lo*2048 (prescaled so lo stays in normal f16
// range; MFMA flushes subnormal inputs which would kill the correction)
DEVI HL split2(float x) {
    HL r;
    r.hi = (_Float16)x;
    r.lo = (_Float16)((x - (float)r.hi) * LO_SCALE);
    return r;
}

// async global->LDS, 16B per lane, LDS dest = wave-uniform base + lane*16
DEVI void gload16(const void* g, void* l) {
    __builtin_amdgcn_global_load_lds(
        (const __attribute__((address_space(1))) unsigned int*)g,
        (__attribute__((address_space(3))) unsigned int*)l,
        16, 0, 0);
}

// ---------------------------------------------------------------------------
// dtype conversion kernels (one-time, memory-bound)
// ---------------------------------------------------------------------------
__global__ __launch_bounds__(256) void cvt_split_k(
    const float* __restrict__ srcA, _Float16* __restrict__ hiA, _Float16* __restrict__ loA,
    const float* __restrict__ srcB, _Float16* __restrict__ hiB, _Float16* __restrict__ loB,
    int n8)
{
    const float* s  = blockIdx.y ? srcB : srcA;
    _Float16*    ph = blockIdx.y ? hiB  : hiA;
    _Float16*    pl = blockIdx.y ? loB  : loA;
    const int idx = blockIdx.x * 256 + threadIdx.x;
    if (idx >= n8) return;
    f32x4 x0 = *(const f32x4*)(s + (size_t)idx * 8);
    f32x4 x1 = *(const f32x4*)(s + (size_t)idx * 8 + 4);
    f16x8 h, l;
#pragma unroll
    for (int j = 0; j < 4; j++) {
        HL p0 = split2(x0[j]), p1 = split2(x1[j]);
        h[j] = p0.hi; l[j] = p0.lo;
        h[4 + j] = p1.hi; l[4 + j] = p1.lo;
    }
    *(f16x8*)(ph + (size_t)idx * 8) = h;
    *(f16x8*)(pl + (size_t)idx * 8) = l;
}

__global__ __launch_bounds__(256) void cvt_f16_k(
    const float* __restrict__ srcA, _Float16* __restrict__ dstA,
    const float* __restrict__ srcB, _Float16* __restrict__ dstB, int n8)
{
    const float* s = blockIdx.y ? srcB : srcA;
    _Float16*    d = blockIdx.y ? dstB : dstA;
    const int idx = blockIdx.x * 256 + threadIdx.x;
    if (idx >= n8) return;
    f32x4 x0 = *(const f32x4*)(s + (size_t)idx * 8);
    f32x4 x1 = *(const f32x4*)(s + (size_t)idx * 8 + 4);
    f16x8 o;
#pragma unroll
    for (int j = 0; j < 4; j++) { o[j] = (_Float16)x0[j]; o[4 + j] = (_Float16)x1[j]; }
    *(f16x8*)(d + (size_t)idx * 8) = o;
}

// ---------------------------------------------------------------------------
// m97-structure GEMM: C[m,n] = sum_k A[m,k]*W[n,k] + bias[n], K = 1024.
// 128x128 tile, BK=32, 4 waves, global_load_lds staging, 2-barrier K-loop.
// COMP: A/W have hi+scaled-lo pairs; 3-term compensated MFMA (f32-accurate).
// ---------------------------------------------------------------------------
DEVI void stage8(const _Float16* gbase, _Float16* ltile, int w, int lane, int k0) {
#pragma unroll
    for (int c = 0; c < 2; c++) {
        const int chunk = 2 * w + c;
        const int row = chunk * 16 + (lane >> 2);
        gload16(gbase + (size_t)row * Dn + k0 + (lane & 3) * 8, ltile + chunk * 512);
    }
}

template<int MODE, bool COMP>
DEVI void gemm2_body(
    const _Float16* __restrict__ A_hi, const _Float16* __restrict__ A_lo,
    const _Float16* __restrict__ W_hi, const _Float16* __restrict__ W_lo,
    const float* __restrict__ bias, void* __restrict__ out0, void* __restrict__ out1)
{
    __shared__ _Float16 lds[(COMP ? 4 : 2) * 4096];
    _Float16* sAh = lds;
    _Float16* sWh = lds + 4096;
    _Float16* sAl = COMP ? lds + 8192  : lds;
    _Float16* sWl = COMP ? lds + 12288 : lds;

    const int l  = threadIdx.x & 63;
    const int w  = threadIdx.x >> 6;
    const int m0 = blockIdx.x * 128;
    const int n0 = blockIdx.y * 128;
    const int wm = (w & 1) * 64, wn = (w >> 1) * 64;
    const int rr = l & 15, ko = (l >> 4) * 8;

    const _Float16* Abh = A_hi + (size_t)m0 * Dn;
    const _Float16* Wbh = W_hi + (size_t)n0 * Dn;
    const _Float16* Abl = COMP ? A_lo + (size_t)m0 * Dn : nullptr;
    const _Float16* Wbl = COMP ? W_lo + (size_t)n0 * Dn : nullptr;

    f32x4 acc[4][4] = {};
    f32x4 accc[4][4] = {};

    for (int k0 = 0; k0 < Dn; k0 += 32) {
        stage8(Abh, sAh, w, l, k0);
        stage8(Wbh, sWh, w, l, k0);
        if (COMP) {
            stage8(Abl, sAl, w, l, k0);
            stage8(Wbl, sWl, w, l, k0);
        }
        __syncthreads();

        f16x8 af[4], bf[4], alf[4], blf[4];
#pragma unroll
        for (int i = 0; i < 4; i++) {
            af[i] = *(const f16x8*)&sAh[(wm + 16 * i + rr) * 32 + ko];
            bf[i] = *(const f16x8*)&sWh[(wn + 16 * i + rr) * 32 + ko];
            if (COMP) {
                alf[i] = *(const f16x8*)&sAl[(wm + 16 * i + rr) * 32 + ko];
                blf[i] = *(const f16x8*)&sWl[(wn + 16 * i + rr) * 32 + ko];
            }
        }
#pragma unroll
        for (int i = 0; i < 4; i++)
#pragma unroll
            for (int j = 0; j < 4; j++) {
                acc[i][j] = mfma_f16(af[i], bf[j], acc[i][j]);
                if (COMP) {
                    accc[i][j] = mfma_f16(alf[i], bf[j], accc[i][j]);
                    accc[i][j] = mfma_f16(af[i], blf[j], accc[i][j]);
                }
            }
        __syncthreads();
    }

#pragma unroll
    for (int i = 0; i < 4; i++)
#pragma unroll
        for (int j = 0; j < 4; j++)
#pragma unroll
            for (int r = 0; r < 4; r++) {
                const int m = m0 + wm + 16 * i + (l >> 4) * 4 + r;
                const int n = n0 + wn + 16 * j + (l & 15);
                float v = acc[i][j][r];
                if (COMP) v += accc[i][j][r] * LO_INV;
                v += bias[n];
                if (MODE == 0) {
                    ((float*)out0)[(size_t)m * Dn + n] = v;
                } else if (MODE == 1) {
                    size_t idx = ((size_t)((m >> 12) * Hn + (n >> 6)) * Ln
                                  + (m & (Ln - 1))) * DKn + (n & 63);
                    ((_Float16*)out0)[idx] = (_Float16)v;
                } else {
                    size_t idx = ((size_t)(n >> 6) * Ln + m) * DKn + (n & 63);
                    HL p = split2(v);
                    ((_Float16*)out0)[idx] = p.hi;
                    ((_Float16*)out1)[idx] = p.lo;
                }
            }
}

__global__ __launch_bounds__(256) void gemm_v_k(
    const _Float16* __restrict__ xv, const _Float16* __restrict__ Wv,
    const float* __restrict__ bv, _Float16* __restrict__ Vstage)
{
    gemm2_body<1, false>(xv, nullptr, Wv, nullptr, bv, Vstage, nullptr);
}

__global__ __launch_bounds__(256) void gemm_o_k(
    const _Float16* __restrict__ Y, const _Float16* __restrict__ Wo,
    const float* __restrict__ bo, float* __restrict__ out)
{
    gemm2_body<0, false>(Y, nullptr, Wo, nullptr, bo, out, nullptr);
}

__global__ __launch_bounds__(256) void gemm_qk_k(
    const _Float16* __restrict__ xqhi, const _Float16* __restrict__ xqlo,
    const _Float16* __restrict__ xkhi, const _Float16* __restrict__ xklo,
    const _Float16* __restrict__ Wqhi, const _Float16* __restrict__ Wqlo,
    const _Float16* __restrict__ Wkhi, const _Float16* __restrict__ Wklo,
    const float* __restrict__ bq, const float* __restrict__ bk,
    _Float16* __restrict__ Qhi, _Float16* __restrict__ Qlo,
    _Float16* __restrict__ Khi, _Float16* __restrict__ Klo)
{
    if (blockIdx.z == 0)
        gemm2_body<2, true>(xqhi, xqlo, Wqhi, Wqlo, bq, Qhi, Qlo);
    else
        gemm2_body<2, true>(xkhi, xklo, Wkhi, Wklo, bk, Khi, Klo);
}

// ---------------------------------------------------------------------------
// Correlation v6 (one batch): v5 + 4-way s-range split for occupancy/TLP.
// 1-D grid of 4096. Physical block P: xcd = P&7; idx = P>>3 in [0,512):
//   h = (P&7)*2 + (idx>>8), band t0 = ((idx>>2)&63)*64, s-quarter sq = idx&3.
// Each XCD still hosts exactly 2 heads (4 MB Q/K = its L2). Wave w covers
// si in [sq*64 + w*16, +16). Partial sums go to corrp[sq] (no atomics);
// topk sums the 4 partials. Zero-copy 8-slot K ring + prefetch as v4/v5.
// ---------------------------------------------------------------------------
__global__ __launch_bounds__(256) void corr_k(
    const _Float16* __restrict__ Qhi, const _Float16* __restrict__ Qlo,
    const _Float16* __restrict__ Khi, const _Float16* __restrict__ Klo,
    float* __restrict__ corr /* corrp + b*Hn*Ln; quarter stride QSTRIDE */)
{
    __shared__ float red[64];
    const int P   = blockIdx.x;
    const int idx = P >> 3;
    const int h   = (P & 7) * 2 + (idx >> 8);
    const int t0  = ((idx >> 2) & 63) * 64;
    const int sq  = idx & 3;
    const int l  = threadIdx.x & 63;
    const int w  = threadIdx.x >> 6;
    const int rr = l & 15;
    const int kf = (l >> 4) * 8;
    const size_t base = (size_t)h * Ln * DKn;
    const _Float16* Qh = Qhi + base;
    const _Float16* Ql = Qlo + base;
    const _Float16* Kh = Khi + base;
    const _Float16* Kl = Klo + base;
    const int lofs = rr * DKn + kf;   // per-lane offset (one VGPR)

    if (threadIdx.x < 64) red[threadIdx.x] = 0.f;
    __syncthreads();

    f16x8 kh0[8], kh1[8], kl0[8], kl1[8];   // K ring, slot = si & 7
    f16x8 qh0[2], qh1[2], ql0[2], ql1[2];   // Q ring, slot = si & 1
    f32x4 th[5] = {}, tc[5] = {};

    const int si0 = sq * 64 + w * 16;       // si0 % 8 == 0

    // prologue: K(si0-4 .. si0+2) -> slots 4..7,0..2 ; Q(si0), Q(si0+1)
#pragma unroll
    for (int p = 0; p < 7; p++) {
        const int si = si0 - 4 + p;
        const int s  = (si0 - 4 + p) & 7;
        const size_t o = (size_t)(((si * 16 - t0) & (Ln - 1))) * DKn + lofs;
        kh0[s] = *(const f16x8*)(Kh + o);
        kh1[s] = *(const f16x8*)(Kh + o + 32);
        kl0[s] = *(const f16x8*)(Kl + o);
        kl1[s] = *(const f16x8*)(Kl + o + 32);
    }
#pragma unroll
    for (int p = 0; p < 2; p++) {
        const size_t o = (size_t)(((si0 + p) * 16) & (Ln - 1)) * DKn + lofs;
        qh0[p] = *(const f16x8*)(Qh + o);
        qh1[p] = *(const f16x8*)(Qh + o + 32);
        ql0[p] = *(const f16x8*)(Ql + o);
        ql1[p] = *(const f16x8*)(Ql + o + 32);
    }

#pragma unroll 1
    for (int g = 0; g < 2; g++) {
#pragma unroll
        for (int u = 0; u < 8; u++) {
            const int si = si0 + g * 8 + u;
            // prefetch K(si+3) -> slot (u+3)&7
            const size_t ko = (size_t)(((si + 3) * 16 - t0) & (Ln - 1)) * DKn + lofs;
            f16x8 nkh0 = *(const f16x8*)(Kh + ko);
            f16x8 nkh1 = *(const f16x8*)(Kh + ko + 32);
            f16x8 nkl0 = *(const f16x8*)(Kl + ko);
            f16x8 nkl1 = *(const f16x8*)(Kl + ko + 32);
            // prefetch Q(si+2) -> slot u&1
            const size_t qo = (size_t)(((si + 2) * 16) & (Ln - 1)) * DKn + lofs;
            f16x8 nqh0 = *(const f16x8*)(Qh + qo);
            f16x8 nqh1 = *(const f16x8*)(Qh + qo + 32);
            f16x8 nql0 = *(const f16x8*)(Ql + qo);
            f16x8 nql1 = *(const f16x8*)(Ql + qo + 32);

#pragma unroll
            for (int j = 0; j <= 4; j++) {
                const int s = (u - j) & 7;
                th[j] = mfma_f16(qh0[u & 1], kh0[s], th[j]);
                th[j] = mfma_f16(qh1[u & 1], kh1[s], th[j]);
                tc[j] = mfma_f16(ql0[u & 1], kh0[s], tc[j]);
                tc[j] = mfma_f16(qh0[u & 1], kl0[s], tc[j]);
                tc[j] = mfma_f16(ql1[u & 1], kh1[s], tc[j]);
                tc[j] = mfma_f16(qh1[u & 1], kl1[s], tc[j]);
            }
            kh0[(u + 3) & 7] = nkh0; kh1[(u + 3) & 7] = nkh1;
            kl0[(u + 3) & 7] = nkl0; kl1[(u + 3) & 7] = nkl1;
            qh0[u & 1] = nqh0; qh1[u & 1] = nqh1;
            ql0[u & 1] = nql0; ql1[u & 1] = nql1;
        }
    }

#pragma unroll
    for (int r = 0; r < 4; r++) {
        const int d  = (l >> 4) * 4 + r - rr;   // a - b
        const int dl = d & 15;
        const bool pos = d >= 0;
#pragma unroll
        for (int i = 0; i < 4; i++) {
            const float hh = pos ? th[i][r] : th[i + 1][r];
            const float cc = pos ? tc[i][r] : tc[i + 1][r];
            atomicAdd(&red[dl + 16 * i], hh + cc * LO_INV);
        }
    }
    __syncthreads();
    if (threadIdx.x < 64)
        corr[(size_t)sq * QSTRIDE + (size_t)h * Ln + t0 + threadIdx.x] = red[threadIdx.x];
}

// ---------------------------------------------------------------------------
// Top-8 + softmax per (b,h): sums the 4 s-quarter partials on load.
// ---------------------------------------------------------------------------
__global__ __launch_bounds__(256) void topk_k(
    const float* __restrict__ corrp, float* __restrict__ top_w,
    int* __restrict__ top_idx)
{
    __shared__ float vals[Ln];
    __shared__ float rv[256];
    __shared__ int   ri[256];
    __shared__ float sel_v[TOPK];
    __shared__ int   sel_i[TOPK];
    const int bh = blockIdx.x;
    const float* c = corrp + (size_t)bh * Ln;
    for (int i = threadIdx.x; i < Ln; i += 256)
        vals[i] = c[i] + c[i + QSTRIDE] + c[i + 2 * QSTRIDE] + c[i + 3 * QSTRIDE];
    __syncthreads();

    for (int it = 0; it < TOPK; it++) {
        float bvv = -1e30f; int bi = 0;
        const int base = threadIdx.x * 16;
#pragma unroll
        for (int j = 0; j < 16; j++) {
            float v = vals[base + j];
            if (v > bvv) { bvv = v; bi = base + j; }
        }
        rv[threadIdx.x] = bvv; ri[threadIdx.x] = bi;
        __syncthreads();
        if (threadIdx.x == 0) {
            float gv = rv[0]; int gi = ri[0];
            for (int t = 1; t < 256; t++)
                if (rv[t] > gv) { gv = rv[t]; gi = ri[t]; }
            sel_v[it] = gv; sel_i[it] = gi;
            vals[gi] = -1e30f;
        }
        __syncthreads();
    }
    if (threadIdx.x == 0) {
        float e[TOPK], s = 0.f;
        for (int i = 0; i < TOPK; i++) {
            e[i] = expf((sel_v[i] - sel_v[0]) * (1.f / 64.f));
            s += e[i];
        }
        for (int i = 0; i < TOPK; i++) {
            top_w[bh * TOPK + i]   = e[i] / s;
            top_idx[bh * TOPK + i] = sel_i[i];
        }
    }
}

// ---------------------------------------------------------------------------
// Aggregation: Y[b][t][h*64+d] = sum_i w_i * V[b][h][(t-idx_i)&4095][d]
// ---------------------------------------------------------------------------
__global__ __launch_bounds__(256) void agg_k(
    const _Float16* __restrict__ V /* [B][H][L][64] */,
    const float* __restrict__ top_w, const int* __restrict__ top_idx,
    _Float16* __restrict__ Y /* [B][L][1024] */)
{
    __shared__ float w_s[TOPK];
    __shared__ int   i_s[TOPK];
    const int bh   = blockIdx.y;
    const int b    = bh >> 4, h = bh & 15;
    const int tloc = threadIdx.x >> 2;
    const int c16  = (threadIdx.x & 3) * 16;
    const int t    = blockIdx.x * 64 + tloc;
    if (threadIdx.x < TOPK) {
        w_s[threadIdx.x] = top_w[bh * TOPK + threadIdx.x];
        i_s[threadIdx.x] = top_idx[bh * TOPK + threadIdx.x];
    }
    __syncthreads();

    const _Float16* Vb = V + (size_t)bh * Ln * DKn;
    float acc[16] = {};
#pragma unroll
    for (int i = 0; i < TOPK; i++) {
        const int src = (t - i_s[i]) & (Ln - 1);
        const _Float16* p = Vb + (size_t)src * DKn + c16;
        f16x8 v0 = *(const f16x8*)(p);
        f16x8 v1 = *(const f16x8*)(p + 8);
        const float wgt = w_s[i];
#pragma unroll
        for (int j = 0; j < 8; j++) acc[j]     += wgt * (float)v0[j];
#pragma unroll
        for (int j = 0; j < 8; j++) acc[8 + j] += wgt * (float)v1[j];
    }
    f16x8 o0, o1;
#pragma unroll
    for (int j = 0; j < 8; j++) { o0[j] = (_Float16)acc[j]; o1[j] = (_Float16)acc[8 + j]; }
    const size_t oidx = ((size_t)(b * Ln + t)) * Dn + h * DKn + c16;
    *(f16x8*)(Y + oidx)     = o0;
    *(f16x8*)(Y + oidx + 8) = o1;
}

// ---------------------------------------------------------------------------
extern "C" void kernel_launch(void* const* d_in, const int* in_sizes, int n_in,
                              void* d_out, int out_size, void* d_ws, size_t ws_size,
                              hipStream_t stream)
{
    const float* q  = (const float*)d_in[0];
    const float* kk = (const float*)d_in[1];
    const float* v  = (const float*)d_in[2];
    const float* Wq = (const float*)d_in[3];
    const float* bq = (const float*)d_in[4];
    const float* Wk = (const float*)d_in[5];
    const float* bk = (const float*)d_in[6];
    const float* Wv = (const float*)d_in[7];
    const float* bv = (const float*)d_in[8];
    const float* Wo = (const float*)d_in[9];
    const float* bo = (const float*)d_in[10];
    float* out = (float*)d_out;

    // ws layout (bytes): as round 7, plus corrp f32 [4][8][16][4096] @ 81797120.
    char* ws = (char*)d_ws;
    if (ws_size < 90185728ull) return;
    _Float16* Qhi  = (_Float16*)(ws);
    _Float16* Qlo  = (_Float16*)(ws + 8388608);
    _Float16* Khi  = (_Float16*)(ws + 16777216);
    _Float16* Klo  = (_Float16*)(ws + 25165824);
    _Float16* xqhi = (_Float16*)(ws + 33554432);
    _Float16* xqlo = (_Float16*)(ws + 41943040);
    _Float16* xkhi = (_Float16*)(ws + 50331648);
    _Float16* xklo = (_Float16*)(ws + 58720256);
    _Float16* Y    = (_Float16*)(ws);
    float*    topw = (float*)(ws + 69206016);
    int*      topi = (int*)(ws + 69210112);
    _Float16* Wqhi = (_Float16*)(ws + 69214208);
    _Float16* Wqlo = (_Float16*)(ws + 71311360);
    _Float16* Wkhi = (_Float16*)(ws + 73408512);
    _Float16* Wklo = (_Float16*)(ws + 75505664);
    _Float16* Wvf  = (_Float16*)(ws + 77602816);
    _Float16* Wof  = (_Float16*)(ws + 79699968);
    float*    corrp = (float*)(ws + 81797120);

    _Float16* Vstage = (_Float16*)d_out;
    _Float16* xvf16  = (_Float16*)((char*)d_out + 67108864);

    cvt_split_k<<<dim3(512, 2), 256, 0, stream>>>(Wq, Wqhi, Wqlo, Wk, Wkhi, Wklo, 131072);
    cvt_f16_k<<<dim3(512, 2), 256, 0, stream>>>(Wv, Wvf, Wo, Wof, 131072);
    cvt_f16_k<<<dim3(16384, 1), 256, 0, stream>>>(v, xvf16, v, xvf16, 4194304);

    gemm_v_k<<<dim3(256, 8), 256, 0, stream>>>(xvf16, Wvf, bv, Vstage);

    for (int b = 0; b < Bn; b++) {
        cvt_split_k<<<dim3(2048, 2), 256, 0, stream>>>(
            q + (size_t)b * Ln * Dn, xqhi, xqlo,
            kk + (size_t)b * Ln * Dn, xkhi, xklo, 524288);
        gemm_qk_k<<<dim3(32, 8, 2), 256, 0, stream>>>(
            xqhi, xqlo, xkhi, xklo,
            Wqhi, Wqlo, Wkhi, Wklo, bq, bk,
            Qhi, Qlo, Khi, Klo);
        corr_k<<<dim3(4096), 256, 0, stream>>>(
            Qhi, Qlo, Khi, Klo, corrp + (size_t)b * Hn * Ln);
    }
    topk_k<<<128, 256, 0, stream>>>(corrp, topw, topi);
    agg_k<<<dim3(64, 128), 256, 0, stream>>>(Vstage, topw, topi, Y);
    gemm_o_k<<<dim3(256, 8), 256, 0, stream>>>(Y, Wof, bo, out);
}

// Round 11
// 2551.329 us; speedup vs baseline: 1.5297x; 1.5297x over previous
//
#include <hip/hip_runtime.h>

#define DEVI static __device__ __forceinline__

typedef float    f32x4 __attribute__((ext_vector_type(4)));
typedef _Float16 f16x8 __attribute__((ext_vector_type(8)));

static constexpr int Bn = 8, Ln = 4096, Dn = 1024, Hn = 16, DKn = 64;
static constexpr int TOPK = 8;
static constexpr float LO_SCALE = 2048.f, LO_INV = 1.f / 2048.f;

DEVI f32x4 mfma_f16(f16x8 a, f16x8 b, f32x4 c) {
    return __builtin_amdgcn_mfma_f32_16x16x32_f16(a, b, c, 0, 0, 0);
}

struct HL { _Float16 hi, lo; };
// split f32 -> f16 hi + f16 lo*2048 (prescaled so lo stays in normal f16
// range; MFMA flushes subnormal inputs which would kill the correction)
DEVI HL split2(float x) {
    HL r;
    r.hi = (_Float16)x;
    r.lo = (_Float16)((x - (float)r.hi) * LO_SCALE);
    return r;
}

// async global->LDS, 16B per lane, LDS dest = wave-uniform base + lane*16
DEVI void gload16(const void* g, void* l) {
    __builtin_amdgcn_global_load_lds(
        (const __attribute__((address_space(1))) unsigned int*)g,
        (__attribute__((address_space(3))) unsigned int*)l,
        16, 0, 0);
}

// ---------------------------------------------------------------------------
// dtype conversion kernels (one-time, memory-bound)
// ---------------------------------------------------------------------------
__global__ __launch_bounds__(256) void cvt_split_k(
    const float* __restrict__ srcA, _Float16* __restrict__ hiA, _Float16* __restrict__ loA,
    const float* __restrict__ srcB, _Float16* __restrict__ hiB, _Float16* __restrict__ loB,
    int n8)
{
    const float* s  = blockIdx.y ? srcB : srcA;
    _Float16*    ph = blockIdx.y ? hiB  : hiA;
    _Float16*    pl = blockIdx.y ? loB  : loA;
    const int idx = blockIdx.x * 256 + threadIdx.x;
    if (idx >= n8) return;
    f32x4 x0 = *(const f32x4*)(s + (size_t)idx * 8);
    f32x4 x1 = *(const f32x4*)(s + (size_t)idx * 8 + 4);
    f16x8 h, l;
#pragma unroll
    for (int j = 0; j < 4; j++) {
        HL p0 = split2(x0[j]), p1 = split2(x1[j]);
        h[j] = p0.hi; l[j] = p0.lo;
        h[4 + j] = p1.hi; l[4 + j] = p1.lo;
    }
    *(f16x8*)(ph + (size_t)idx * 8) = h;
    *(f16x8*)(pl + (size_t)idx * 8) = l;
}

__global__ __launch_bounds__(256) void cvt_f16_k(
    const float* __restrict__ srcA, _Float16* __restrict__ dstA,
    const float* __restrict__ srcB, _Float16* __restrict__ dstB, int n8)
{
    const float* s = blockIdx.y ? srcB : srcA;
    _Float16*    d = blockIdx.y ? dstB : dstA;
    const int idx = blockIdx.x * 256 + threadIdx.x;
    if (idx >= n8) return;
    f32x4 x0 = *(const f32x4*)(s + (size_t)idx * 8);
    f32x4 x1 = *(const f32x4*)(s + (size_t)idx * 8 + 4);
    f16x8 o;
#pragma unroll
    for (int j = 0; j < 4; j++) { o[j] = (_Float16)x0[j]; o[4 + j] = (_Float16)x1[j]; }
    *(f16x8*)(d + (size_t)idx * 8) = o;
}

// ---------------------------------------------------------------------------
// m97-structure GEMM: C[m,n] = sum_k A[m,k]*W[n,k] + bias[n], K = 1024.
// 128x128 tile, BK=32, 4 waves, global_load_lds staging, 2-barrier K-loop.
// COMP: A/W have hi+scaled-lo pairs; 3-term compensated MFMA (f32-accurate).
// ---------------------------------------------------------------------------
DEVI void stage8(const _Float16* gbase, _Float16* ltile, int w, int lane, int k0) {
#pragma unroll
    for (int c = 0; c < 2; c++) {
        const int chunk = 2 * w + c;
        const int row = chunk * 16 + (lane >> 2);
        gload16(gbase + (size_t)row * Dn + k0 + (lane & 3) * 8, ltile + chunk * 512);
    }
}

template<int MODE, bool COMP>
DEVI void gemm2_body(
    const _Float16* __restrict__ A_hi, const _Float16* __restrict__ A_lo,
    const _Float16* __restrict__ W_hi, const _Float16* __restrict__ W_lo,
    const float* __restrict__ bias, void* __restrict__ out0, void* __restrict__ out1)
{
    __shared__ _Float16 lds[(COMP ? 4 : 2) * 4096];
    _Float16* sAh = lds;
    _Float16* sWh = lds + 4096;
    _Float16* sAl = COMP ? lds + 8192  : lds;
    _Float16* sWl = COMP ? lds + 12288 : lds;

    const int l  = threadIdx.x & 63;
    const int w  = threadIdx.x >> 6;
    const int m0 = blockIdx.x * 128;
    const int n0 = blockIdx.y * 128;
    const int wm = (w & 1) * 64, wn = (w >> 1) * 64;
    const int rr = l & 15, ko = (l >> 4) * 8;

    const _Float16* Abh = A_hi + (size_t)m0 * Dn;
    const _Float16* Wbh = W_hi + (size_t)n0 * Dn;
    const _Float16* Abl = COMP ? A_lo + (size_t)m0 * Dn : nullptr;
    const _Float16* Wbl = COMP ? W_lo + (size_t)n0 * Dn : nullptr;

    f32x4 acc[4][4] = {};
    f32x4 accc[4][4] = {};

    for (int k0 = 0; k0 < Dn; k0 += 32) {
        stage8(Abh, sAh, w, l, k0);
        stage8(Wbh, sWh, w, l, k0);
        if (COMP) {
            stage8(Abl, sAl, w, l, k0);
            stage8(Wbl, sWl, w, l, k0);
        }
        __syncthreads();

        f16x8 af[4], bf[4], alf[4], blf[4];
#pragma unroll
        for (int i = 0; i < 4; i++) {
            af[i] = *(const f16x8*)&sAh[(wm + 16 * i + rr) * 32 + ko];
            bf[i] = *(const f16x8*)&sWh[(wn + 16 * i + rr) * 32 + ko];
            if (COMP) {
                alf[i] = *(const f16x8*)&sAl[(wm + 16 * i + rr) * 32 + ko];
                blf[i] = *(const f16x8*)&sWl[(wn + 16 * i + rr) * 32 + ko];
            }
        }
#pragma unroll
        for (int i = 0; i < 4; i++)
#pragma unroll
            for (int j = 0; j < 4; j++) {
                acc[i][j] = mfma_f16(af[i], bf[j], acc[i][j]);
                if (COMP) {
                    accc[i][j] = mfma_f16(alf[i], bf[j], accc[i][j]);
                    accc[i][j] = mfma_f16(af[i], blf[j], accc[i][j]);
                }
            }
        __syncthreads();
    }

#pragma unroll
    for (int i = 0; i < 4; i++)
#pragma unroll
        for (int j = 0; j < 4; j++)
#pragma unroll
            for (int r = 0; r < 4; r++) {
                const int m = m0 + wm + 16 * i + (l >> 4) * 4 + r;
                const int n = n0 + wn + 16 * j + (l & 15);
                float v = acc[i][j][r];
                if (COMP) v += accc[i][j][r] * LO_INV;
                v += bias[n];
                if (MODE == 0) {
                    ((float*)out0)[(size_t)m * Dn + n] = v;
                } else if (MODE == 1) {
                    size_t idx = ((size_t)((m >> 12) * Hn + (n >> 6)) * Ln
                                  + (m & (Ln - 1))) * DKn + (n & 63);
                    ((_Float16*)out0)[idx] = (_Float16)v;
                } else {
                    size_t idx = ((size_t)(n >> 6) * Ln + m) * DKn + (n & 63);
                    HL p = split2(v);
                    ((_Float16*)out0)[idx] = p.hi;
                    ((_Float16*)out1)[idx] = p.lo;
                }
            }
}

__global__ __launch_bounds__(256) void gemm_v_k(
    const _Float16* __restrict__ xv, const _Float16* __restrict__ Wv,
    const float* __restrict__ bv, _Float16* __restrict__ Vstage)
{
    gemm2_body<1, false>(xv, nullptr, Wv, nullptr, bv, Vstage, nullptr);
}

__global__ __launch_bounds__(256) void gemm_o_k(
    const _Float16* __restrict__ Y, const _Float16* __restrict__ Wo,
    const float* __restrict__ bo, float* __restrict__ out)
{
    gemm2_body<0, false>(Y, nullptr, Wo, nullptr, bo, out, nullptr);
}

__global__ __launch_bounds__(256) void gemm_qk_k(
    const _Float16* __restrict__ xqhi, const _Float16* __restrict__ xqlo,
    const _Float16* __restrict__ xkhi, const _Float16* __restrict__ xklo,
    const _Float16* __restrict__ Wqhi, const _Float16* __restrict__ Wqlo,
    const _Float16* __restrict__ Wkhi, const _Float16* __restrict__ Wklo,
    const float* __restrict__ bq, const float* __restrict__ bk,
    _Float16* __restrict__ Qhi, _Float16* __restrict__ Qlo,
    _Float16* __restrict__ Khi, _Float16* __restrict__ Klo)
{
    if (blockIdx.z == 0)
        gemm2_body<2, true>(xqhi, xqlo, Wqhi, Wqlo, bq, Qhi, Qlo);
    else
        gemm2_body<2, true>(xkhi, xklo, Wkhi, Wklo, bk, Khi, Klo);
}

// ---------------------------------------------------------------------------
// Correlation v7 (one batch): LDS-staged m97-style band kernel.
// Block = (head h, 64-diagonal band t0), XCD-swizzled as v5 (round 9).
// 64 chunks of 64 s-rows. Per chunk: stage Q chunk + K chunk (ring of 2;
// compute needs K chunks c-1 and c) via global_load_lds; 2-barrier loop.
// LDS buffers are XOR-swizzled (group ^= row&7) to kill the 128B-row-stride
// bank conflict on ds_read_b128; gload_lds dest stays LINEAR, the global
// SOURCE address is pre-swizzled (both-sides rule).
// Wave w computes si-tile c*4+w; 5 tile positions j=0..4:
//   Tj row = (si-j)*16 - t0 + rr -> K slot (c + ((w-j)>>2))&1,
//   local row ((w-j)&3)*16 + rr. 24 ds_read_b128 / 30 MFMA per wave-chunk.
// grid: 1024 blocks, 256 threads. LDS 48.25KB -> 3 blocks/CU.
// ---------------------------------------------------------------------------
__global__ __launch_bounds__(256) void corr_k(
    const _Float16* __restrict__ Qhi, const _Float16* __restrict__ Qlo,
    const _Float16* __restrict__ Khi, const _Float16* __restrict__ Klo,
    float* __restrict__ corr /* [16][4096] of this batch */)
{
    __shared__ _Float16 sK[2][8192];   // [slot][part*4096 + row*64 + col]
    __shared__ _Float16 sQ[8192];
    __shared__ float red[64];

    const int P   = blockIdx.x;
    const int idx = P >> 3;
    const int h   = (P & 7) * 2 + (idx >> 6);   // XCD x hosts heads 2x,2x+1
    const int t0  = (idx & 63) * 64;
    const int l   = threadIdx.x & 63;
    const int w   = threadIdx.x >> 6;
    const int rr  = l & 15;
    const int kf  = (l >> 4) * 8;
    const size_t base = (size_t)h * Ln * DKn;
    const _Float16* Qh = Qhi + base;
    const _Float16* Ql = Qlo + base;
    const _Float16* Kh = Khi + base;
    const _Float16* Kl = Klo + base;

    if (threadIdx.x < 64) red[threadIdx.x] = 0.f;

    // staging lane geometry: each gload16 call covers 8 rows x 64 f16.
    const int lr  = l >> 3;            // row within the 8-row call
    const int gsw = (l & 7) ^ lr;      // pre-swizzled source group (involution)

    f32x4 th[5] = {}, tc[5] = {};

    // prologue: K chunk -1 -> slot 1
    {
#pragma unroll
        for (int cc = 0; cc < 2; cc++) {
            const int Rb = w * 16 + cc * 8;
            const int grow = (-64 - t0 + Rb + lr) & (Ln - 1);
            gload16(Kh + (size_t)grow * DKn + gsw * 8, &sK[1][Rb * 64]);
            gload16(Kl + (size_t)grow * DKn + gsw * 8, &sK[1][4096 + Rb * 64]);
        }
    }

    for (int c = 0; c < 64; c++) {
        // stage K chunk c -> slot c&1, Q chunk c
#pragma unroll
        for (int cc = 0; cc < 2; cc++) {
            const int Rb = w * 16 + cc * 8;
            const int kgrow = (c * 64 - t0 + Rb + lr) & (Ln - 1);
            const int qgrow = c * 64 + Rb + lr;
            gload16(Kh + (size_t)kgrow * DKn + gsw * 8, &sK[c & 1][Rb * 64]);
            gload16(Kl + (size_t)kgrow * DKn + gsw * 8, &sK[c & 1][4096 + Rb * 64]);
            gload16(Qh + (size_t)qgrow * DKn + gsw * 8, &sQ[Rb * 64]);
            gload16(Ql + (size_t)qgrow * DKn + gsw * 8, &sQ[4096 + Rb * 64]);
        }
        __syncthreads();   // drains vmcnt + barrier: all staged data visible

        // Q fragments for si-tile c*4+w (local rows w*16 + rr)
        const int qr = w * 16 + rr;
        const int qsw0 = ((kf >> 3) ^ (qr & 7)) * 8;
        const int qsw1 = (((32 + kf) >> 3) ^ (qr & 7)) * 8;
        f16x8 qh0 = *(const f16x8*)&sQ[qr * 64 + qsw0];
        f16x8 qh1 = *(const f16x8*)&sQ[qr * 64 + qsw1];
        f16x8 ql0 = *(const f16x8*)&sQ[4096 + qr * 64 + qsw0];
        f16x8 ql1 = *(const f16x8*)&sQ[4096 + qr * 64 + qsw1];

#pragma unroll
        for (int j = 0; j <= 4; j++) {
            const int slot = (c + ((w - j) >> 2)) & 1;
            const int kr   = ((w - j) & 3) * 16 + rr;
            const int ksw0 = ((kf >> 3) ^ (kr & 7)) * 8;
            const int ksw1 = (((32 + kf) >> 3) ^ (kr & 7)) * 8;
            f16x8 kh0 = *(const f16x8*)&sK[slot][kr * 64 + ksw0];
            f16x8 kh1 = *(const f16x8*)&sK[slot][kr * 64 + ksw1];
            f16x8 kl0 = *(const f16x8*)&sK[slot][4096 + kr * 64 + ksw0];
            f16x8 kl1 = *(const f16x8*)&sK[slot][4096 + kr * 64 + ksw1];
            th[j] = mfma_f16(qh0, kh0, th[j]);
            th[j] = mfma_f16(qh1, kh1, th[j]);
            tc[j] = mfma_f16(ql0, kh0, tc[j]);
            tc[j] = mfma_f16(qh0, kl0, tc[j]);
            tc[j] = mfma_f16(ql1, kh1, tc[j]);
            tc[j] = mfma_f16(qh1, kl1, tc[j]);
        }
        __syncthreads();   // protect slot (c-1)&1 (= (c+1)&1) before re-stage
    }

#pragma unroll
    for (int r = 0; r < 4; r++) {
        const int d  = (l >> 4) * 4 + r - rr;   // a - b
        const int dl = d & 15;
        const bool pos = d >= 0;
#pragma unroll
        for (int i = 0; i < 4; i++) {
            const float hh = pos ? th[i][r] : th[i + 1][r];
            const float cc = pos ? tc[i][r] : tc[i + 1][r];
            atomicAdd(&red[dl + 16 * i], hh + cc * LO_INV);
        }
    }
    __syncthreads();
    if (threadIdx.x < 64)
        corr[(size_t)h * Ln + t0 + threadIdx.x] = red[threadIdx.x];
}

// ---------------------------------------------------------------------------
// Top-8 + softmax per (b,h) row of corr (raw sums; /64 before softmax).
// ---------------------------------------------------------------------------
__global__ __launch_bounds__(256) void topk_k(
    const float* __restrict__ corr, float* __restrict__ top_w,
    int* __restrict__ top_idx)
{
    __shared__ float vals[Ln];
    __shared__ float rv[256];
    __shared__ int   ri[256];
    __shared__ float sel_v[TOPK];
    __shared__ int   sel_i[TOPK];
    const int bh = blockIdx.x;
    const float* c = corr + (size_t)bh * Ln;
    for (int i = threadIdx.x; i < Ln; i += 256) vals[i] = c[i];
    __syncthreads();

    for (int it = 0; it < TOPK; it++) {
        float bvv = -1e30f; int bi = 0;
        const int base = threadIdx.x * 16;
#pragma unroll
        for (int j = 0; j < 16; j++) {
            float v = vals[base + j];
            if (v > bvv) { bvv = v; bi = base + j; }
        }
        rv[threadIdx.x] = bvv; ri[threadIdx.x] = bi;
        __syncthreads();
        if (threadIdx.x == 0) {
            float gv = rv[0]; int gi = ri[0];
            for (int t = 1; t < 256; t++)
                if (rv[t] > gv) { gv = rv[t]; gi = ri[t]; }
            sel_v[it] = gv; sel_i[it] = gi;
            vals[gi] = -1e30f;
        }
        __syncthreads();
    }
    if (threadIdx.x == 0) {
        float e[TOPK], s = 0.f;
        for (int i = 0; i < TOPK; i++) {
            e[i] = expf((sel_v[i] - sel_v[0]) * (1.f / 64.f));
            s += e[i];
        }
        for (int i = 0; i < TOPK; i++) {
            top_w[bh * TOPK + i]   = e[i] / s;
            top_idx[bh * TOPK + i] = sel_i[i];
        }
    }
}

// ---------------------------------------------------------------------------
// Aggregation: Y[b][t][h*64+d] = sum_i w_i * V[b][h][(t-idx_i)&4095][d]
// ---------------------------------------------------------------------------
__global__ __launch_bounds__(256) void agg_k(
    const _Float16* __restrict__ V /* [B][H][L][64] */,
    const float* __restrict__ top_w, const int* __restrict__ top_idx,
    _Float16* __restrict__ Y /* [B][L][1024] */)
{
    __shared__ float w_s[TOPK];
    __shared__ int   i_s[TOPK];
    const int bh   = blockIdx.y;
    const int b    = bh >> 4, h = bh & 15;
    const int tloc = threadIdx.x >> 2;
    const int c16  = (threadIdx.x & 3) * 16;
    const int t    = blockIdx.x * 64 + tloc;
    if (threadIdx.x < TOPK) {
        w_s[threadIdx.x] = top_w[bh * TOPK + threadIdx.x];
        i_s[threadIdx.x] = top_idx[bh * TOPK + threadIdx.x];
    }
    __syncthreads();

    const _Float16* Vb = V + (size_t)bh * Ln * DKn;
    float acc[16] = {};
#pragma unroll
    for (int i = 0; i < TOPK; i++) {
        const int src = (t - i_s[i]) & (Ln - 1);
        const _Float16* p = Vb + (size_t)src * DKn + c16;
        f16x8 v0 = *(const f16x8*)(p);
        f16x8 v1 = *(const f16x8*)(p + 8);
        const float wgt = w_s[i];
#pragma unroll
        for (int j = 0; j < 8; j++) acc[j]     += wgt * (float)v0[j];
#pragma unroll
        for (int j = 0; j < 8; j++) acc[8 + j] += wgt * (float)v1[j];
    }
    f16x8 o0, o1;
#pragma unroll
    for (int j = 0; j < 8; j++) { o0[j] = (_Float16)acc[j]; o1[j] = (_Float16)acc[8 + j]; }
    const size_t oidx = ((size_t)(b * Ln + t)) * Dn + h * DKn + c16;
    *(f16x8*)(Y + oidx)     = o0;
    *(f16x8*)(Y + oidx + 8) = o1;
}

// ---------------------------------------------------------------------------
extern "C" void kernel_launch(void* const* d_in, const int* in_sizes, int n_in,
                              void* d_out, int out_size, void* d_ws, size_t ws_size,
                              hipStream_t stream)
{
    const float* q  = (const float*)d_in[0];
    const float* kk = (const float*)d_in[1];
    const float* v  = (const float*)d_in[2];
    const float* Wq = (const float*)d_in[3];
    const float* bq = (const float*)d_in[4];
    const float* Wk = (const float*)d_in[5];
    const float* bk = (const float*)d_in[6];
    const float* Wv = (const float*)d_in[7];
    const float* bv = (const float*)d_in[8];
    const float* Wo = (const float*)d_in[9];
    const float* bo = (const float*)d_in[10];
    float* out = (float*)d_out;

    // ws layout: as round 7 (corr single buffer @ 67108864).
    char* ws = (char*)d_ws;
    if (ws_size < 81797120ull) return;
    _Float16* Qhi  = (_Float16*)(ws);
    _Float16* Qlo  = (_Float16*)(ws + 8388608);
    _Float16* Khi  = (_Float16*)(ws + 16777216);
    _Float16* Klo  = (_Float16*)(ws + 25165824);
    _Float16* xqhi = (_Float16*)(ws + 33554432);
    _Float16* xqlo = (_Float16*)(ws + 41943040);
    _Float16* xkhi = (_Float16*)(ws + 50331648);
    _Float16* xklo = (_Float16*)(ws + 58720256);
    _Float16* Y    = (_Float16*)(ws);
    float*    corr = (float*)(ws + 67108864);
    float*    topw = (float*)(ws + 69206016);
    int*      topi = (int*)(ws + 69210112);
    _Float16* Wqhi = (_Float16*)(ws + 69214208);
    _Float16* Wqlo = (_Float16*)(ws + 71311360);
    _Float16* Wkhi = (_Float16*)(ws + 73408512);
    _Float16* Wklo = (_Float16*)(ws + 75505664);
    _Float16* Wvf  = (_Float16*)(ws + 77602816);
    _Float16* Wof  = (_Float16*)(ws + 79699968);

    _Float16* Vstage = (_Float16*)d_out;
    _Float16* xvf16  = (_Float16*)((char*)d_out + 67108864);

    cvt_split_k<<<dim3(512, 2), 256, 0, stream>>>(Wq, Wqhi, Wqlo, Wk, Wkhi, Wklo, 131072);
    cvt_f16_k<<<dim3(512, 2), 256, 0, stream>>>(Wv, Wvf, Wo, Wof, 131072);
    cvt_f16_k<<<dim3(16384, 1), 256, 0, stream>>>(v, xvf16, v, xvf16, 4194304);

    gemm_v_k<<<dim3(256, 8), 256, 0, stream>>>(xvf16, Wvf, bv, Vstage);

    for (int b = 0; b < Bn; b++) {
        cvt_split_k<<<dim3(2048, 2), 256, 0, stream>>>(
            q + (size_t)b * Ln * Dn, xqhi, xqlo,
            kk + (size_t)b * Ln * Dn, xkhi, xklo, 524288);
        gemm_qk_k<<<dim3(32, 8, 2), 256, 0, stream>>>(
            xqhi, xqlo, xkhi, xklo,
            Wqhi, Wqlo, Wkhi, Wklo, bq, bk,
            Qhi, Qlo, Khi, Klo);
        corr_k<<<dim3(1024), 256, 0, stream>>>(
            Qhi, Qlo, Khi, Klo, corr + (size_t)b * Hn * Ln);
    }
    topk_k<<<128, 256, 0, stream>>>(corr, topw, topi);
    agg_k<<<dim3(64, 128), 256, 0, stream>>>(Vstage, topw, topi, Y);
    gemm_o_k<<<dim3(256, 8), 256, 0, stream>>>(Y, Wof, bo, out);
}